// Round 1
// baseline (1582.305 us; speedup 1.0000x reference)
//
#include <hip/hip_runtime.h>
#include <hip/hip_bf16.h>
#include <cstdint>
#include <cstddef>

// Problem constants (match reference)
#define E_TOT   1048576
#define BG      64
#define NN      1024
#define DD      128
#define AIN     112      // 32 pooled + 64 edges + 8 globs + 8 cndts
#define HID     256
#define NH      4
#define NSEG    65536    // B*N

// ---------------------------------------------------------------------------
// K0: transpose W1 [112][256] -> W1T [256][112] so hidden-j rows are contiguous
// ---------------------------------------------------------------------------
__global__ __launch_bounds__(256)
void k_transpose_w1(const float* __restrict__ W1, float* __restrict__ W1T) {
    int idx = blockIdx.x * 256 + threadIdx.x;   // idx = k*256 + j
    if (idx >= AIN * HID) return;
    int k = idx >> 8;
    int j = idx & 255;
    W1T[j * AIN + k] = W1[idx];
}

// ---------------------------------------------------------------------------
// K1: per-edge MLP -> logits -> ex = exp(logit)  (segment-max skipped: logits
// are O(few), exp cannot overflow fp32, and the max cancels in the softmax).
// Also accumulates the softmax denominator and the per-segment histogram.
// Thread-per-edge; x in VGPRs; W1T staged into LDS in two 128-hidden halves.
// ---------------------------------------------------------------------------
__global__ __launch_bounds__(256, 2)
void k_mlp(const float* __restrict__ pooled, const float* __restrict__ edges,
           const float* __restrict__ globs,  const float* __restrict__ cndts,
           const float* __restrict__ W1T,    const float* __restrict__ b1,
           const float* __restrict__ W2,     const float* __restrict__ b2,
           const int* __restrict__ batch_idx, const int* __restrict__ recv_idx,
           float* __restrict__ ex_out, float* __restrict__ denom,
           int* __restrict__ counts)
{
    __shared__ float sW[128 * AIN];   // 57,344 B (one hidden-half of W1T)
    __shared__ float sB1[HID];        // 1 KB
    __shared__ float sW2[HID * NH];   // 4 KB

    const int tid = threadIdx.x;
    const int e   = blockIdx.x * 256 + tid;

    // stage b1 / W2 once
    sB1[tid] = b1[tid];
    #pragma unroll
    for (int i = 0; i < 4; ++i) sW2[i * 256 + tid] = W2[i * 256 + tid];

    // load x = [pooled(32) | edges(64) | globs(8) | cndts(8)] into registers
    float x[AIN];
    {
        const float4* pm = reinterpret_cast<const float4*>(pooled + (size_t)e * 32);
        #pragma unroll
        for (int i = 0; i < 8; ++i) {
            float4 v = pm[i];
            x[i*4+0]=v.x; x[i*4+1]=v.y; x[i*4+2]=v.z; x[i*4+3]=v.w;
        }
        const float4* eg = reinterpret_cast<const float4*>(edges + (size_t)e * 64);
        #pragma unroll
        for (int i = 0; i < 16; ++i) {
            float4 v = eg[i];
            x[32+i*4+0]=v.x; x[32+i*4+1]=v.y; x[32+i*4+2]=v.z; x[32+i*4+3]=v.w;
        }
    }
    const int b = batch_idx[e];
    {
        const float4* gp = reinterpret_cast<const float4*>(globs + (size_t)b * 8);
        #pragma unroll
        for (int i = 0; i < 2; ++i) {
            float4 v = gp[i];
            x[96+i*4+0]=v.x; x[96+i*4+1]=v.y; x[96+i*4+2]=v.z; x[96+i*4+3]=v.w;
        }
        const float4* cp = reinterpret_cast<const float4*>(cndts + (size_t)b * 8);
        #pragma unroll
        for (int i = 0; i < 2; ++i) {
            float4 v = cp[i];
            x[104+i*4+0]=v.x; x[104+i*4+1]=v.y; x[104+i*4+2]=v.z; x[104+i*4+3]=v.w;
        }
    }

    float acc[NH] = { b2[0], b2[1], b2[2], b2[3] };

    for (int half = 0; half < 2; ++half) {
        __syncthreads();
        // stage one 128-hidden half of W1T: 14336 floats = 3584 float4
        const float4* src = reinterpret_cast<const float4*>(W1T + (size_t)half * 128 * AIN);
        float4* dst = reinterpret_cast<float4*>(sW);
        #pragma unroll
        for (int i = 0; i < 14; ++i) dst[i * 256 + tid] = src[i * 256 + tid];
        __syncthreads();

        for (int jj = 0; jj < 128; ++jj) {
            const float4* w = reinterpret_cast<const float4*>(&sW[jj * AIN]);
            float s0 = 0.f, s1 = 0.f, s2 = 0.f, s3 = 0.f;
            #pragma unroll
            for (int k4 = 0; k4 < 28; ++k4) {
                float4 wv = w[k4];                 // uniform LDS broadcast
                s0 = fmaf(x[k4*4+0], wv.x, s0);
                s1 = fmaf(x[k4*4+1], wv.y, s1);
                s2 = fmaf(x[k4*4+2], wv.z, s2);
                s3 = fmaf(x[k4*4+3], wv.w, s3);
            }
            const int j = half * 128 + jj;
            float s  = (s0 + s1) + (s2 + s3) + sB1[j];
            float hv = s > 0.f ? s : 0.1f * s;     // leaky_relu(0.1)
            const float4 w2v = *reinterpret_cast<const float4*>(&sW2[j * 4]);
            acc[0] = fmaf(hv, w2v.x, acc[0]);
            acc[1] = fmaf(hv, w2v.y, acc[1]);
            acc[2] = fmaf(hv, w2v.z, acc[2]);
            acc[3] = fmaf(hv, w2v.w, acc[3]);
        }
    }

    const float ex0 = expf(acc[0]);
    const float ex1 = expf(acc[1]);
    const float ex2 = expf(acc[2]);
    const float ex3 = expf(acc[3]);

    const int seg = b * NN + recv_idx[e];
    float4 exv; exv.x = ex0; exv.y = ex1; exv.z = ex2; exv.w = ex3;
    *reinterpret_cast<float4*>(ex_out + (size_t)e * 4) = exv;

    atomicAdd(&denom[seg * 4 + 0], ex0);
    atomicAdd(&denom[seg * 4 + 1], ex1);
    atomicAdd(&denom[seg * 4 + 2], ex2);
    atomicAdd(&denom[seg * 4 + 3], ex3);
    atomicAdd(&counts[seg], 1);
}

// ---------------------------------------------------------------------------
// K2: single-block exclusive scan of counts[65536] -> offsets, cursor
// ---------------------------------------------------------------------------
__global__ __launch_bounds__(1024)
void k_scan(const int* __restrict__ counts, int* __restrict__ offsets,
            int* __restrict__ cursor)
{
    __shared__ int ssum[1024];
    const int t = threadIdx.x;
    int s = 0;
    for (int i = 0; i < 64; ++i) s += counts[t * 64 + i];
    ssum[t] = s;
    __syncthreads();
    for (int off = 1; off < 1024; off <<= 1) {
        int v = (t >= off) ? ssum[t - off] : 0;
        __syncthreads();
        ssum[t] += v;
        __syncthreads();
    }
    int run = (t == 0) ? 0 : ssum[t - 1];
    for (int i = 0; i < 64; ++i) {
        int c = counts[t * 64 + i];
        offsets[t * 64 + i] = run;
        cursor[t * 64 + i]  = run;
        run += c;
    }
}

// ---------------------------------------------------------------------------
// K3: scatter edge ids into per-segment lists (counting sort, order-free)
// ---------------------------------------------------------------------------
__global__ __launch_bounds__(256)
void k_scatter(const int* __restrict__ batch_idx, const int* __restrict__ recv_idx,
               int* __restrict__ cursor, int* __restrict__ elist)
{
    int e   = blockIdx.x * 256 + threadIdx.x;
    int seg = batch_idx[e] * NN + recv_idx[e];
    int pos = atomicAdd(&cursor[seg], 1);
    elist[pos] = e;
}

// ---------------------------------------------------------------------------
// K4: one wave per segment; lane owns 2 of the 128 dims; head = lane>>4.
// new_edges read exactly once (coalesced 512B rows); out written exactly once.
// ---------------------------------------------------------------------------
__global__ __launch_bounds__(256)
void k_gather(const float* __restrict__ new_edges, const float* __restrict__ ex,
              const float* __restrict__ denom, const int* __restrict__ offsets,
              const int* __restrict__ counts, const int* __restrict__ elist,
              float* __restrict__ out)
{
    const int gid  = blockIdx.x * 256 + threadIdx.x;
    const int seg  = gid >> 6;
    const int lane = threadIdx.x & 63;
    if (seg >= NSEG) return;

    const int start = offsets[seg];
    const int cnt   = counts[seg];
    const int h     = lane >> 4;                 // head for dims lane*2, lane*2+1
    const float inv = 1.0f / denom[seg * 4 + h]; // unused if cnt==0

    float a0 = 0.f, a1 = 0.f;
    for (int i = 0; i < cnt; ++i) {
        const int el    = elist[start + i];
        const float wgt = ex[(size_t)el * 4 + h] * inv;
        const float2 ne = *reinterpret_cast<const float2*>(
            new_edges + (size_t)el * DD + lane * 2);
        a0 = fmaf(ne.x, wgt, a0);
        a1 = fmaf(ne.y, wgt, a1);
    }
    float2 r; r.x = a0; r.y = a1;
    *reinterpret_cast<float2*>(out + (size_t)seg * DD + lane * 2) = r;
}

// ---------------------------------------------------------------------------
extern "C" void kernel_launch(void* const* d_in, const int* in_sizes, int n_in,
                              void* d_out, int out_size, void* d_ws, size_t ws_size,
                              hipStream_t stream)
{
    const float* new_edges = (const float*)d_in[0];
    const float* edges     = (const float*)d_in[1];
    const float* pooled    = (const float*)d_in[2];
    const float* globs     = (const float*)d_in[3];
    const float* cndts     = (const float*)d_in[4];
    const float* W1        = (const float*)d_in[5];
    const float* b1        = (const float*)d_in[6];
    const float* W2        = (const float*)d_in[7];
    const float* b2        = (const float*)d_in[8];
    const int*   batch_idx = (const int*)d_in[9];
    const int*   recv_idx  = (const int*)d_in[10];
    float* out = (float*)d_out;

    char* ws = (char*)d_ws;
    float* ex     = (float*)(ws);                                   // 16 MB
    float* denom  = (float*)(ws + (size_t)16 * 1024 * 1024);        // 1 MB
    int*   counts = (int*)  (ws + (size_t)17 * 1024 * 1024);        // 256 KB
    int*   offs   = (int*)  (ws + (size_t)17 * 1024 * 1024 + 262144);
    int*   cursor = (int*)  (ws + (size_t)17 * 1024 * 1024 + 2 * 262144);
    int*   elist  = (int*)  (ws + (size_t)17 * 1024 * 1024 + 3 * 262144); // 4 MB
    float* W1T    = (float*)(ws + (size_t)17 * 1024 * 1024 + 3 * 262144
                                 + (size_t)4 * 1024 * 1024);        // 114,688 B

    // denom (1 MB) and counts (256 KB) are contiguous: one memset
    hipMemsetAsync(denom, 0,
                   (size_t)NSEG * NH * sizeof(float) + (size_t)NSEG * sizeof(int),
                   stream);

    k_transpose_w1<<<(AIN * HID) / 256, 256, 0, stream>>>(W1, W1T);
    k_mlp<<<E_TOT / 256, 256, 0, stream>>>(pooled, edges, globs, cndts,
                                           W1T, b1, W2, b2,
                                           batch_idx, recv_idx,
                                           ex, denom, counts);
    k_scan<<<1, 1024, 0, stream>>>(counts, offs, cursor);
    k_scatter<<<E_TOT / 256, 256, 0, stream>>>(batch_idx, recv_idx, cursor, elist);
    k_gather<<<(NSEG * 64) / 256, 256, 0, stream>>>(new_edges, ex, denom,
                                                    offs, counts, elist, out);
}

// Round 2
// 482.584 us; speedup vs baseline: 3.2788x; 3.2788x over previous
//
#include <hip/hip_runtime.h>
#include <hip/hip_bf16.h>
#include <cstdint>
#include <cstddef>

// Problem constants
#define E_TOT   1048576
#define BGR     64
#define NN      1024
#define DD      128
#define HID     256
#define NH      4
#define NSEG    65536
#define KDIM    192          // 2 * 96 (xhi | xlo), ctxt handled separately
#define NKCH    24           // KDIM/8 chunks
#define BM      128          // edges per M-tile
#define NTILES  (E_TOT/BM)   // 8192

typedef __attribute__((ext_vector_type(8))) short s16x8;   // 8 bf16
typedef __attribute__((ext_vector_type(4))) float f32x4;

static __device__ __forceinline__ unsigned short f2bf_rn(float f) {
    unsigned u = __float_as_uint(f);
    unsigned r = u + 0x7FFF + ((u >> 16) & 1);   // round-to-nearest-even
    return (unsigned short)(r >> 16);
}

// ---------------------------------------------------------------------------
// Prep A: build Wg [24 kchunk][256 hidden][8] bf16 — both 96-halves = bf16(W1)
// (2-term split: xhi*w + xlo*w). W1 is [112][256] fp32; rows 96..111 go to ctxtc.
// ---------------------------------------------------------------------------
__global__ __launch_bounds__(256)
void k_prep_w(const float* __restrict__ W1, short* __restrict__ Wg) {
    int idx = blockIdx.x * 256 + threadIdx.x;        // < 24*256*8 = 49152
    int kchunk = idx >> 11;                          // /(256*8)
    int n      = (idx >> 3) & 255;
    int j      = idx & 7;
    int k      = (kchunk % 12) * 8 + j;              // 0..95
    Wg[idx] = (short)f2bf_rn(W1[k * 256 + n]);
}

// ---------------------------------------------------------------------------
// Prep B: ctxtc[64][256] = b1[j] + globs[b]·W1[96:104][j] + cndts[b]·W1[104:112][j]
// ---------------------------------------------------------------------------
__global__ __launch_bounds__(256)
void k_prep_ctx(const float* __restrict__ W1, const float* __restrict__ b1,
                const float* __restrict__ globs, const float* __restrict__ cndts,
                float* __restrict__ ctxtc) {
    int b = blockIdx.x, j = threadIdx.x;
    float s = b1[j];
    #pragma unroll
    for (int g = 0; g < 8; ++g) s = fmaf(globs[b * 8 + g], W1[(96 + g) * 256 + j], s);
    #pragma unroll
    for (int c = 0; c < 8; ++c) s = fmaf(cndts[b * 8 + c], W1[(104 + c) * 256 + j], s);
    ctxtc[b * 256 + j] = s;
}

// ---------------------------------------------------------------------------
// Main fused MFMA kernel: per 128-edge tile:
//   h = leaky(X*W1 + ctxt)  [MFMA, C = hidden x edges]
//   logits = h*W2 (per-lane FMA + shfl + LDS partial over 4 hidden-strip waves)
//   ex = exp(logit); denom/count atomics
// 256 persistent blocks x 512 thr (8 waves: wh=wid>>1 hidden strip, we=wid&1 edge strip)
// ---------------------------------------------------------------------------
__global__ __launch_bounds__(512, 2)
void k_mlp_mfma(const float* __restrict__ pooled, const float* __restrict__ edges,
                const short* __restrict__ Wg,     const float* __restrict__ ctxtc,
                const float* __restrict__ W2,
                const int* __restrict__ batch_idx, const int* __restrict__ recv_idx,
                float* __restrict__ ex_out, float* __restrict__ denom,
                int* __restrict__ counts)
{
    __shared__ short Wl[NKCH * 256 * 8];    // 98304 B  [kchunk][hidden][8]
    __shared__ short Xl[NKCH * 128 * 8];    // 49152 B  [kchunk][edge][8]
    __shared__ float sW2[256 * 4];          // 4096 B
    __shared__ float plog[4 * 128 * 4];     // 8192 B   [wh][edge][head]

    const int tid  = threadIdx.x;
    const int lane = tid & 63;
    const int wid  = tid >> 6;
    const int wh   = wid >> 1;          // hidden strip 0..3 (64 rows each)
    const int we   = wid & 1;           // edge strip 0..1 (64 edges each)
    const int la   = lane & 15;
    const int g    = lane >> 4;         // 0..3

    // ---- prologue: W into LDS (linear copy, layout prebuilt), W2 ----
    {
        const float4* src = reinterpret_cast<const float4*>(Wg);
        float4* dst = reinterpret_cast<float4*>(Wl);
        #pragma unroll
        for (int i = 0; i < 12; ++i) dst[i * 512 + tid] = src[i * 512 + tid];
        if (tid < 256)
            *reinterpret_cast<float4*>(&sW2[tid * 4]) =
                reinterpret_cast<const float4*>(W2)[tid];
    }

    // frag base element offsets (shorts)
    const int kb = g;                       // k-chunk within step = lane>>4
    int wbase[4], xbase[4];
    #pragma unroll
    for (int hf = 0; hf < 4; ++hf) wbase[hf] = (kb * 256 + wh * 64 + hf * 16 + la) * 8;
    #pragma unroll
    for (int ef = 0; ef < 4; ++ef) xbase[ef] = (kb * 128 + we * 64 + ef * 16 + la) * 8;

    const int tile0 = blockIdx.x * (NTILES / 256);
    const int tend  = tile0 + (NTILES / 256);

    // per-thread staging role: edge = tid>>2, quarter q = tid&3 (24 x-elems each)
    const int se_loc = tid >> 2;
    const int sq     = tid & 3;

    // ---- stage tile0 X into LDS ----
    {
        const int eg = tile0 * BM + se_loc;
        float4 sv[6];
        #pragma unroll
        for (int c = 0; c < 6; ++c) {
            int elem = sq * 24 + c * 4;
            const float* p = (elem < 32) ? (pooled + (size_t)eg * 32 + elem)
                                         : (edges + (size_t)eg * 64 + (elem - 32));
            sv[c] = *reinterpret_cast<const float4*>(p);
        }
        #pragma unroll
        for (int c2 = 0; c2 < 3; ++c2) {
            float vals[8] = { sv[2*c2].x, sv[2*c2].y, sv[2*c2].z, sv[2*c2].w,
                              sv[2*c2+1].x, sv[2*c2+1].y, sv[2*c2+1].z, sv[2*c2+1].w };
            s16x8 hv, lv;
            #pragma unroll
            for (int i = 0; i < 8; ++i) {
                unsigned short hb = f2bf_rn(vals[i]);
                hv[i] = (short)hb;
                float rem = vals[i] - __uint_as_float((unsigned)hb << 16);
                lv[i] = (short)f2bf_rn(rem);
            }
            int kch = sq * 3 + c2;
            *reinterpret_cast<s16x8*>(&Xl[(kch * 128 + se_loc) * 8]) = hv;
            *reinterpret_cast<s16x8*>(&Xl[((12 + kch) * 128 + se_loc) * 8]) = lv;
        }
    }
    __syncthreads();

    for (int t = tile0; t < tend; ++t) {
        const int e0 = t * BM;
        const bool has_next = (t + 1 < tend);

        // ---- T14 early: issue next tile's global loads ----
        float4 sv[6];
        if (has_next) {
            const int eg = (t + 1) * BM + se_loc;
            #pragma unroll
            for (int c = 0; c < 6; ++c) {
                int elem = sq * 24 + c * 4;
                const float* p = (elem < 32) ? (pooled + (size_t)eg * 32 + elem)
                                             : (edges + (size_t)eg * 64 + (elem - 32));
                sv[c] = *reinterpret_cast<const float4*>(p);
            }
        }

        // ---- K-loop: 6 steps x (4 hf x 4 ef) MFMA ----
        f32x4 acc[4][4];
        #pragma unroll
        for (int i = 0; i < 4; ++i)
            #pragma unroll
            for (int j = 0; j < 4; ++j) acc[i][j] = (f32x4){0.f, 0.f, 0.f, 0.f};

        #pragma unroll
        for (int ks = 0; ks < 6; ++ks) {
            s16x8 wf[4], xf[4];
            #pragma unroll
            for (int hf = 0; hf < 4; ++hf)
                wf[hf] = *reinterpret_cast<const s16x8*>(&Wl[wbase[hf] + ks * 8192]);
            #pragma unroll
            for (int ef = 0; ef < 4; ++ef)
                xf[ef] = *reinterpret_cast<const s16x8*>(&Xl[xbase[ef] + ks * 4096]);
            #pragma unroll
            for (int hf = 0; hf < 4; ++hf)
                #pragma unroll
                for (int ef = 0; ef < 4; ++ef)
                    acc[hf][ef] = __builtin_amdgcn_mfma_f32_16x16x32_bf16(
                        wf[hf], xf[ef], acc[hf][ef], 0, 0, 0);
        }

        // ---- epilogue part 1: +ctxt, leaky, layer-2 partials, wave reduce ----
        int b_ef[4];
        #pragma unroll
        for (int ef = 0; ef < 4; ++ef)
            b_ef[ef] = batch_idx[e0 + we * 64 + ef * 16 + la];

        float pl[4][4];   // [ef][head]
        #pragma unroll
        for (int i = 0; i < 4; ++i)
            #pragma unroll
            for (int j = 0; j < 4; ++j) pl[i][j] = 0.f;

        #pragma unroll
        for (int hf = 0; hf < 4; ++hf) {
            const int j0 = wh * 64 + hf * 16 + g * 4;   // hidden row of acc reg r=0
            float4 w2r[4];
            #pragma unroll
            for (int r = 0; r < 4; ++r)
                w2r[r] = *reinterpret_cast<const float4*>(&sW2[(j0 + r) * 4]);
            #pragma unroll
            for (int ef = 0; ef < 4; ++ef) {
                const float4 cx = *reinterpret_cast<const float4*>(
                    &ctxtc[(size_t)b_ef[ef] * 256 + j0]);
                const float cxa[4] = {cx.x, cx.y, cx.z, cx.w};
                #pragma unroll
                for (int r = 0; r < 4; ++r) {
                    float s = acc[hf][ef][r] + cxa[r];
                    float h = s > 0.f ? s : 0.1f * s;
                    pl[ef][0] = fmaf(h, w2r[r].x, pl[ef][0]);
                    pl[ef][1] = fmaf(h, w2r[r].y, pl[ef][1]);
                    pl[ef][2] = fmaf(h, w2r[r].z, pl[ef][2]);
                    pl[ef][3] = fmaf(h, w2r[r].w, pl[ef][3]);
                }
            }
        }
        // reduce across the 4 row-groups (lanes ^16, ^32)
        #pragma unroll
        for (int ef = 0; ef < 4; ++ef)
            #pragma unroll
            for (int h = 0; h < 4; ++h) {
                pl[ef][h] += __shfl_xor(pl[ef][h], 16);
                pl[ef][h] += __shfl_xor(pl[ef][h], 32);
            }
        // lane writes ef == g slice (static-index select, rule #20)
        {
            float4 p0 = {pl[0][0], pl[0][1], pl[0][2], pl[0][3]};
            float4 p1 = {pl[1][0], pl[1][1], pl[1][2], pl[1][3]};
            float4 p2 = {pl[2][0], pl[2][1], pl[2][2], pl[2][3]};
            float4 p3 = {pl[3][0], pl[3][1], pl[3][2], pl[3][3]};
            float4 o = (g == 0) ? p0 : (g == 1) ? p1 : (g == 2) ? p2 : p3;
            const int eloc = we * 64 + g * 16 + la;
            *reinterpret_cast<float4*>(&plog[(wh * 128 + eloc) * 4]) = o;
        }
        __syncthreads();   // barrier1: K-loop reads done; plog visible

        // ---- epilogue part 2: final logits -> ex + atomics ----
        {
            const int e  = tid >> 2;
            const int h  = tid & 3;
            const int eg = e0 + e;
            float lg = plog[(0 * 128 + e) * 4 + h] + plog[(1 * 128 + e) * 4 + h]
                     + plog[(2 * 128 + e) * 4 + h] + plog[(3 * 128 + e) * 4 + h];
            float exv = expf(lg);
            ex_out[(size_t)eg * 4 + h] = exv;
            const int seg = batch_idx[eg] * NN + recv_idx[eg];
            atomicAdd(&denom[seg * 4 + h], exv);
            if (h == 0) atomicAdd(&counts[seg], 1);
        }

        // ---- write next tile's X into LDS ----
        if (has_next) {
            #pragma unroll
            for (int c2 = 0; c2 < 3; ++c2) {
                float vals[8] = { sv[2*c2].x, sv[2*c2].y, sv[2*c2].z, sv[2*c2].w,
                                  sv[2*c2+1].x, sv[2*c2+1].y, sv[2*c2+1].z, sv[2*c2+1].w };
                s16x8 hv, lv;
                #pragma unroll
                for (int i = 0; i < 8; ++i) {
                    unsigned short hb = f2bf_rn(vals[i]);
                    hv[i] = (short)hb;
                    float rem = vals[i] - __uint_as_float((unsigned)hb << 16);
                    lv[i] = (short)f2bf_rn(rem);
                }
                int kch = sq * 3 + c2;
                *reinterpret_cast<s16x8*>(&Xl[(kch * 128 + se_loc) * 8]) = hv;
                *reinterpret_cast<s16x8*>(&Xl[((12 + kch) * 128 + se_loc) * 8]) = lv;
            }
        }
        __syncthreads();   // barrier2: Xl(t+1) ready; plog reusable
    }
}

// ---------------------------------------------------------------------------
// K2: single-block exclusive scan of counts[65536] -> offsets, cursor
// ---------------------------------------------------------------------------
__global__ __launch_bounds__(1024)
void k_scan(const int* __restrict__ counts, int* __restrict__ offsets,
            int* __restrict__ cursor)
{
    __shared__ int ssum[1024];
    const int t = threadIdx.x;
    int s = 0;
    for (int i = 0; i < 64; ++i) s += counts[t * 64 + i];
    ssum[t] = s;
    __syncthreads();
    for (int off = 1; off < 1024; off <<= 1) {
        int v = (t >= off) ? ssum[t - off] : 0;
        __syncthreads();
        ssum[t] += v;
        __syncthreads();
    }
    int run = (t == 0) ? 0 : ssum[t - 1];
    for (int i = 0; i < 64; ++i) {
        int c = counts[t * 64 + i];
        offsets[t * 64 + i] = run;
        cursor[t * 64 + i]  = run;
        run += c;
    }
}

// ---------------------------------------------------------------------------
// K3: scatter edge ids into per-segment lists (counting sort)
// ---------------------------------------------------------------------------
__global__ __launch_bounds__(256)
void k_scatter(const int* __restrict__ batch_idx, const int* __restrict__ recv_idx,
               int* __restrict__ cursor, int* __restrict__ elist)
{
    int e   = blockIdx.x * 256 + threadIdx.x;
    int seg = batch_idx[e] * NN + recv_idx[e];
    int pos = atomicAdd(&cursor[seg], 1);
    elist[pos] = e;
}

// ---------------------------------------------------------------------------
// K4: one wave per segment; lane owns 2 of 128 dims; head = lane>>4
// ---------------------------------------------------------------------------
__global__ __launch_bounds__(256)
void k_gather(const float* __restrict__ new_edges, const float* __restrict__ ex,
              const float* __restrict__ denom, const int* __restrict__ offsets,
              const int* __restrict__ counts, const int* __restrict__ elist,
              float* __restrict__ out)
{
    const int gid  = blockIdx.x * 256 + threadIdx.x;
    const int seg  = gid >> 6;
    const int lane = threadIdx.x & 63;
    if (seg >= NSEG) return;

    const int start = offsets[seg];
    const int cnt   = counts[seg];
    const int h     = lane >> 4;
    const float inv = 1.0f / denom[seg * 4 + h];

    float a0 = 0.f, a1 = 0.f;
    for (int i = 0; i < cnt; ++i) {
        const int el    = elist[start + i];
        const float wgt = ex[(size_t)el * 4 + h] * inv;
        const float2 ne = *reinterpret_cast<const float2*>(
            new_edges + (size_t)el * DD + lane * 2);
        a0 = fmaf(ne.x, wgt, a0);
        a1 = fmaf(ne.y, wgt, a1);
    }
    float2 r; r.x = a0; r.y = a1;
    *reinterpret_cast<float2*>(out + (size_t)seg * DD + lane * 2) = r;
}

// ---------------------------------------------------------------------------
extern "C" void kernel_launch(void* const* d_in, const int* in_sizes, int n_in,
                              void* d_out, int out_size, void* d_ws, size_t ws_size,
                              hipStream_t stream)
{
    const float* new_edges = (const float*)d_in[0];
    const float* edges     = (const float*)d_in[1];
    const float* pooled    = (const float*)d_in[2];
    const float* globs     = (const float*)d_in[3];
    const float* cndts     = (const float*)d_in[4];
    const float* W1        = (const float*)d_in[5];
    const float* b1        = (const float*)d_in[6];
    const float* W2        = (const float*)d_in[7];
    // b2 (d_in[8]) cancels in the per-head softmax — intentionally unused
    const int*   batch_idx = (const int*)d_in[9];
    const int*   recv_idx  = (const int*)d_in[10];
    float* out = (float*)d_out;

    char* ws = (char*)d_ws;
    float* ex     = (float*)(ws);                                    // 16 MB
    float* denom  = (float*)(ws + (size_t)16 * 1024 * 1024);         // 1 MB
    int*   counts = (int*)  (ws + (size_t)17 * 1024 * 1024);         // 256 KB
    int*   offs   = (int*)  (ws + (size_t)17 * 1024 * 1024 + 262144);
    int*   cursor = (int*)  (ws + (size_t)17 * 1024 * 1024 + 2 * 262144);
    int*   elist  = (int*)  (ws + (size_t)17 * 1024 * 1024 + 3 * 262144); // 4 MB
    short* Wg     = (short*)(ws + (size_t)17 * 1024 * 1024 + 3 * 262144
                                 + (size_t)4 * 1024 * 1024);         // 98,304 B
    float* ctxtc  = (float*)(ws + (size_t)17 * 1024 * 1024 + 3 * 262144
                                 + (size_t)4 * 1024 * 1024 + 98304); // 65,536 B

    hipMemsetAsync(denom, 0,
                   (size_t)NSEG * NH * sizeof(float) + (size_t)NSEG * sizeof(int),
                   stream);

    k_prep_w<<<192, 256, 0, stream>>>(W1, Wg);
    k_prep_ctx<<<64, 256, 0, stream>>>(W1, b1, globs, cndts, ctxtc);
    k_mlp_mfma<<<256, 512, 0, stream>>>(pooled, edges, Wg, ctxtc, W2,
                                        batch_idx, recv_idx, ex, denom, counts);
    k_scan<<<1, 1024, 0, stream>>>(counts, offs, cursor);
    k_scatter<<<E_TOT / 256, 256, 0, stream>>>(batch_idx, recv_idx, cursor, elist);
    k_gather<<<(NSEG * 64) / 256, 256, 0, stream>>>(new_edges, ex, denom,
                                                    offs, counts, elist, out);
}

// Round 3
// 423.094 us; speedup vs baseline: 3.7398x; 1.1406x over previous
//
#include <hip/hip_runtime.h>
#include <hip/hip_bf16.h>
#include <cstdint>
#include <cstddef>

// Problem constants
#define E_TOT   1048576
#define BGR     64
#define NN      1024
#define DD      128
#define HID     256
#define NH      4
#define NSEG    65536
#define KDIM    96           // x in bf16 (no hi/lo split); ctxt folded separately
#define NKCH    12           // KDIM/8 chunks
#define BM      128          // edges per M-tile
#define NTILES  (E_TOT/BM)   // 8192
#define TPB     (NTILES/256) // 32 tiles per persistent block

typedef __attribute__((ext_vector_type(8))) short s16x8;   // 8 bf16
typedef __attribute__((ext_vector_type(4))) float f32x4;

static __device__ __forceinline__ unsigned short f2bf_rn(float f) {
    unsigned u = __float_as_uint(f);
    unsigned r = u + 0x7FFF + ((u >> 16) & 1);   // round-to-nearest-even
    return (unsigned short)(r >> 16);
}

// ---------------------------------------------------------------------------
// Prep A: Wg [12 kchunk][256 hidden][8] bf16 = bf16(W1[0:96])  (MFMA A layout)
// ---------------------------------------------------------------------------
__global__ __launch_bounds__(256)
void k_prep_w(const float* __restrict__ W1, short* __restrict__ Wg) {
    int idx = blockIdx.x * 256 + threadIdx.x;        // < 12*256*8 = 24576
    int kchunk = idx >> 11;
    int n      = (idx >> 3) & 255;
    int j      = idx & 7;
    int k      = kchunk * 8 + j;                     // 0..95
    Wg[idx] = (short)f2bf_rn(W1[k * 256 + n]);
}

// ---------------------------------------------------------------------------
// Prep B: ctxtc[64][256] = b1 + globs[b]·W1[96:104] + cndts[b]·W1[104:112]
// ---------------------------------------------------------------------------
__global__ __launch_bounds__(256)
void k_prep_ctx(const float* __restrict__ W1, const float* __restrict__ b1,
                const float* __restrict__ globs, const float* __restrict__ cndts,
                float* __restrict__ ctxtc) {
    int b = blockIdx.x, j = threadIdx.x;
    float s = b1[j];
    #pragma unroll
    for (int g = 0; g < 8; ++g) s = fmaf(globs[b * 8 + g], W1[(96 + g) * 256 + j], s);
    #pragma unroll
    for (int c = 0; c < 8; ++c) s = fmaf(cndts[b * 8 + c], W1[(104 + c) * 256 + j], s);
    ctxtc[b * 256 + j] = s;
}

// ---------------------------------------------------------------------------
// Count edges per segment (separate from MLP so the scan chain is independent)
// ---------------------------------------------------------------------------
__global__ __launch_bounds__(256)
void k_count(const int* __restrict__ batch_idx, const int* __restrict__ recv_idx,
             int* __restrict__ counts)
{
    int e = blockIdx.x * 256 + threadIdx.x;
    atomicAdd(&counts[batch_idx[e] * NN + recv_idx[e]], 1);
}

// ---------------------------------------------------------------------------
// Parallel exclusive scan of counts[65536]: 3 small kernels
// ---------------------------------------------------------------------------
__global__ __launch_bounds__(256)
void k_scan1(const int* __restrict__ counts, int* __restrict__ tmp_excl,
             int* __restrict__ blocksums)
{
    __shared__ int sh[256];
    const int t = threadIdx.x;
    const int gid = blockIdx.x * 256 + t;
    int c = counts[gid];
    sh[t] = c;
    __syncthreads();
    int v = c;
    for (int off = 1; off < 256; off <<= 1) {
        int u = (t >= off) ? sh[t - off] : 0;
        __syncthreads();
        v += u; sh[t] = v;
        __syncthreads();
    }
    tmp_excl[gid] = v - c;                    // exclusive
    if (t == 255) blocksums[blockIdx.x] = v;  // block total
}

__global__ __launch_bounds__(256)
void k_scan2(int* __restrict__ blocksums)
{
    __shared__ int sh[256];
    const int t = threadIdx.x;
    int c = blocksums[t];
    sh[t] = c;
    __syncthreads();
    int v = c;
    for (int off = 1; off < 256; off <<= 1) {
        int u = (t >= off) ? sh[t - off] : 0;
        __syncthreads();
        v += u; sh[t] = v;
        __syncthreads();
    }
    blocksums[t] = v - c;                     // exclusive block offset
}

__global__ __launch_bounds__(256)
void k_scan3(const int* __restrict__ tmp_excl, const int* __restrict__ blocksums,
             int* __restrict__ offsets, int* __restrict__ cursor)
{
    const int gid = blockIdx.x * 256 + threadIdx.x;
    int v = tmp_excl[gid] + blocksums[blockIdx.x];
    offsets[gid] = v;
    cursor[gid]  = v;
}

// ---------------------------------------------------------------------------
// K3: scatter edge ids into per-segment lists (counting sort)
// ---------------------------------------------------------------------------
__global__ __launch_bounds__(256)
void k_scatter(const int* __restrict__ batch_idx, const int* __restrict__ recv_idx,
               int* __restrict__ cursor, int* __restrict__ elist)
{
    int e   = blockIdx.x * 256 + threadIdx.x;
    int seg = batch_idx[e] * NN + recv_idx[e];
    int pos = atomicAdd(&cursor[seg], 1);
    elist[pos] = e;
}

// ---------------------------------------------------------------------------
// Main fused MFMA kernel (K=96 bf16). 256 persistent blocks x 512 threads,
// 8 waves = 4 hidden strips x 2 edge strips. One barrier per tile via
// Xl[2] / plog[2] ping-pong. T14: next tile's global loads issued pre-K-loop.
// ---------------------------------------------------------------------------
__global__ __launch_bounds__(512, 2)
void k_mlp_mfma(const float* __restrict__ pooled, const float* __restrict__ edges,
                const short* __restrict__ Wg,     const float* __restrict__ ctxtc,
                const float* __restrict__ W2,
                const int* __restrict__ batch_idx, const int* __restrict__ recv_idx,
                float* __restrict__ ex_out, float* __restrict__ denom)
{
    __shared__ short Wl[NKCH * 256 * 8];        // 49152 B [kchunk][hidden][8]
    __shared__ short Xl[2][NKCH * 128 * 8];     // 49152 B [buf][kchunk][edge][8]
    __shared__ float sW2[256 * 4];              //  4096 B
    __shared__ float plog[2][4 * 128 * 4];      // 16384 B [buf][wh][edge][head]

    const int tid  = threadIdx.x;
    const int lane = tid & 63;
    const int wid  = tid >> 6;
    const int wh   = wid >> 1;          // hidden strip 0..3 (64 rows)
    const int we   = wid & 1;           // edge strip 0..1 (64 edges)
    const int la   = lane & 15;
    const int g    = lane >> 4;         // 0..3

    // ---- prologue: W (layout prebuilt) + W2 into LDS ----
    {
        const float4* src = reinterpret_cast<const float4*>(Wg);
        float4* dst = reinterpret_cast<float4*>(Wl);
        #pragma unroll
        for (int i = 0; i < 6; ++i) dst[i * 512 + tid] = src[i * 512 + tid];
        if (tid < 256)
            *reinterpret_cast<float4*>(&sW2[tid * 4]) =
                reinterpret_cast<const float4*>(W2)[tid];
    }

    // frag base element offsets (shorts); k-chunk within step = g
    int wbase[4], xbase[4];
    #pragma unroll
    for (int hf = 0; hf < 4; ++hf) wbase[hf] = (g * 256 + wh * 64 + hf * 16 + la) * 8;
    #pragma unroll
    for (int ef = 0; ef < 4; ++ef) xbase[ef] = (g * 128 + we * 64 + ef * 16 + la) * 8;

    const int tile0 = blockIdx.x * TPB;
    const int tend  = tile0 + TPB;

    // staging role: edge = tid>>2, quarter sq = tid&3 (24 x-elems each)
    const int se_loc = tid >> 2;
    const int sq     = tid & 3;

    // ---- stage tile0 into Xl[0] ----
    {
        const int eg = tile0 * BM + se_loc;
        #pragma unroll
        for (int c2 = 0; c2 < 3; ++c2) {
            float4 v0, v1;
            {
                int elem = sq * 24 + c2 * 8;
                const float* p = (elem < 32) ? (pooled + (size_t)eg * 32 + elem)
                                             : (edges + (size_t)eg * 64 + (elem - 32));
                v0 = *reinterpret_cast<const float4*>(p);
                elem += 4;
                const float* q = (elem < 32) ? (pooled + (size_t)eg * 32 + elem)
                                             : (edges + (size_t)eg * 64 + (elem - 32));
                v1 = *reinterpret_cast<const float4*>(q);
            }
            float vals[8] = { v0.x, v0.y, v0.z, v0.w, v1.x, v1.y, v1.z, v1.w };
            s16x8 hv;
            #pragma unroll
            for (int i = 0; i < 8; ++i) hv[i] = (short)f2bf_rn(vals[i]);
            int kch = sq * 3 + c2;
            *reinterpret_cast<s16x8*>(&Xl[0][(kch * 128 + se_loc) * 8]) = hv;
        }
    }
    __syncthreads();

    for (int t = tile0; t < tend; ++t) {
        const int li  = t - tile0;
        const int cur = li & 1;
        const int nxt = cur ^ 1;
        const int e0  = t * BM;
        const bool has_next = (t + 1 < tend);

        // ---- T14 early: issue next tile's global loads ----
        float4 sv[6];
        if (has_next) {
            const int eg = (t + 1) * BM + se_loc;
            #pragma unroll
            for (int c = 0; c < 6; ++c) {
                int elem = sq * 24 + c * 4;
                const float* p = (elem < 32) ? (pooled + (size_t)eg * 32 + elem)
                                             : (edges + (size_t)eg * 64 + (elem - 32));
                sv[c] = *reinterpret_cast<const float4*>(p);
            }
        }

        // ---- K-loop: 3 steps x (4 hf x 4 ef) MFMA ----
        f32x4 acc[4][4];
        #pragma unroll
        for (int i = 0; i < 4; ++i)
            #pragma unroll
            for (int j = 0; j < 4; ++j) acc[i][j] = (f32x4){0.f, 0.f, 0.f, 0.f};

        #pragma unroll
        for (int ks = 0; ks < 3; ++ks) {
            s16x8 wf[4], xf[4];
            #pragma unroll
            for (int hf = 0; hf < 4; ++hf)
                wf[hf] = *reinterpret_cast<const s16x8*>(&Wl[wbase[hf] + ks * 8192]);
            #pragma unroll
            for (int ef = 0; ef < 4; ++ef)
                xf[ef] = *reinterpret_cast<const s16x8*>(&Xl[cur][xbase[ef] + ks * 4096]);
            #pragma unroll
            for (int hf = 0; hf < 4; ++hf)
                #pragma unroll
                for (int ef = 0; ef < 4; ++ef)
                    acc[hf][ef] = __builtin_amdgcn_mfma_f32_16x16x32_bf16(
                        wf[hf], xf[ef], acc[hf][ef], 0, 0, 0);
        }

        // ---- convert + write next tile into Xl[nxt] (own K-loop reads done;
        //      other waves read Xl[cur] — different buffer, safe pre-barrier) ----
        if (has_next) {
            #pragma unroll
            for (int c2 = 0; c2 < 3; ++c2) {
                float vals[8] = { sv[2*c2].x, sv[2*c2].y, sv[2*c2].z, sv[2*c2].w,
                                  sv[2*c2+1].x, sv[2*c2+1].y, sv[2*c2+1].z, sv[2*c2+1].w };
                s16x8 hv;
                #pragma unroll
                for (int i = 0; i < 8; ++i) hv[i] = (short)f2bf_rn(vals[i]);
                int kch = sq * 3 + c2;
                *reinterpret_cast<s16x8*>(&Xl[nxt][(kch * 128 + se_loc) * 8]) = hv;
            }
        }

        // ---- epilogue 1: +ctxt, leaky, layer-2 partials, wave reduce ----
        int b_ef[4];
        #pragma unroll
        for (int ef = 0; ef < 4; ++ef)
            b_ef[ef] = batch_idx[e0 + we * 64 + ef * 16 + la];

        float pl[4][4];   // [ef][head]
        #pragma unroll
        for (int i = 0; i < 4; ++i)
            #pragma unroll
            for (int j = 0; j < 4; ++j) pl[i][j] = 0.f;

        #pragma unroll
        for (int hf = 0; hf < 4; ++hf) {
            const int j0 = wh * 64 + hf * 16 + g * 4;   // hidden row of acc reg r=0
            float4 w2r[4];
            #pragma unroll
            for (int r = 0; r < 4; ++r)
                w2r[r] = *reinterpret_cast<const float4*>(&sW2[(j0 + r) * 4]);
            #pragma unroll
            for (int ef = 0; ef < 4; ++ef) {
                const float4 cx = *reinterpret_cast<const float4*>(
                    &ctxtc[(size_t)b_ef[ef] * 256 + j0]);
                const float cxa[4] = {cx.x, cx.y, cx.z, cx.w};
                #pragma unroll
                for (int r = 0; r < 4; ++r) {
                    float s = acc[hf][ef][r] + cxa[r];
                    float h = s > 0.f ? s : 0.1f * s;
                    pl[ef][0] = fmaf(h, w2r[r].x, pl[ef][0]);
                    pl[ef][1] = fmaf(h, w2r[r].y, pl[ef][1]);
                    pl[ef][2] = fmaf(h, w2r[r].z, pl[ef][2]);
                    pl[ef][3] = fmaf(h, w2r[r].w, pl[ef][3]);
                }
            }
        }
        #pragma unroll
        for (int ef = 0; ef < 4; ++ef)
            #pragma unroll
            for (int h = 0; h < 4; ++h) {
                pl[ef][h] += __shfl_xor(pl[ef][h], 16);
                pl[ef][h] += __shfl_xor(pl[ef][h], 32);
            }
        {
            float4 p0 = {pl[0][0], pl[0][1], pl[0][2], pl[0][3]};
            float4 p1 = {pl[1][0], pl[1][1], pl[1][2], pl[1][3]};
            float4 p2 = {pl[2][0], pl[2][1], pl[2][2], pl[2][3]};
            float4 p3 = {pl[3][0], pl[3][1], pl[3][2], pl[3][3]};
            float4 o = (g == 0) ? p0 : (g == 1) ? p1 : (g == 2) ? p2 : p3;
            const int eloc = we * 64 + g * 16 + la;
            *reinterpret_cast<float4*>(&plog[cur][(wh * 128 + eloc) * 4]) = o;
        }
        __syncthreads();   // single barrier: plog[cur] visible; Xl[nxt] ready

        // ---- epilogue 2: final logits -> ex + denom atomics ----
        {
            const int e  = tid >> 2;
            const int h  = tid & 3;
            const int eg = e0 + e;
            float lg = plog[cur][(0 * 128 + e) * 4 + h] + plog[cur][(1 * 128 + e) * 4 + h]
                     + plog[cur][(2 * 128 + e) * 4 + h] + plog[cur][(3 * 128 + e) * 4 + h];
            float exv = expf(lg);
            ex_out[(size_t)eg * 4 + h] = exv;
            const int seg = batch_idx[eg] * NN + recv_idx[eg];
            atomicAdd(&denom[seg * 4 + h], exv);
        }
    }
}

// ---------------------------------------------------------------------------
// K4: one wave per segment; lane owns 2 of 128 dims; head = lane>>4
// ---------------------------------------------------------------------------
__global__ __launch_bounds__(256)
void k_gather(const float* __restrict__ new_edges, const float* __restrict__ ex,
              const float* __restrict__ denom, const int* __restrict__ offsets,
              const int* __restrict__ counts, const int* __restrict__ elist,
              float* __restrict__ out)
{
    const int gid  = blockIdx.x * 256 + threadIdx.x;
    const int seg  = gid >> 6;
    const int lane = threadIdx.x & 63;
    if (seg >= NSEG) return;

    const int start = offsets[seg];
    const int cnt   = counts[seg];
    const int h     = lane >> 4;
    const float inv = 1.0f / denom[seg * 4 + h];

    float a0 = 0.f, a1 = 0.f;
    for (int i = 0; i < cnt; ++i) {
        const int el    = elist[start + i];
        const float wgt = ex[(size_t)el * 4 + h] * inv;
        const float2 ne = *reinterpret_cast<const float2*>(
            new_edges + (size_t)el * DD + lane * 2);
        a0 = fmaf(ne.x, wgt, a0);
        a1 = fmaf(ne.y, wgt, a1);
    }
    float2 r; r.x = a0; r.y = a1;
    *reinterpret_cast<float2*>(out + (size_t)seg * DD + lane * 2) = r;
}

// ---------------------------------------------------------------------------
extern "C" void kernel_launch(void* const* d_in, const int* in_sizes, int n_in,
                              void* d_out, int out_size, void* d_ws, size_t ws_size,
                              hipStream_t stream)
{
    const float* new_edges = (const float*)d_in[0];
    const float* edges     = (const float*)d_in[1];
    const float* pooled    = (const float*)d_in[2];
    const float* globs     = (const float*)d_in[3];
    const float* cndts     = (const float*)d_in[4];
    const float* W1        = (const float*)d_in[5];
    const float* b1        = (const float*)d_in[6];
    const float* W2        = (const float*)d_in[7];
    // b2 (d_in[8]) cancels in the per-head softmax — intentionally unused
    const int*   batch_idx = (const int*)d_in[9];
    const int*   recv_idx  = (const int*)d_in[10];
    float* out = (float*)d_out;

    char* ws = (char*)d_ws;
    float* ex       = (float*)(ws);                              // 16 MB
    float* denom    = (float*)(ws + (size_t)16 * 1024 * 1024);   // 1 MB
    char*  base17   = ws + (size_t)17 * 1024 * 1024;
    int*   counts   = (int*)(base17);                            // 256 KB
    int*   offs     = (int*)(base17 + 1 * 262144);
    int*   cursor   = (int*)(base17 + 2 * 262144);
    int*   tmp_excl = (int*)(base17 + 3 * 262144);
    int*   bsums    = (int*)(base17 + 4 * 262144);               // 1 KB
    int*   elist    = (int*)(ws + (size_t)18 * 1024 * 1024);     // 4 MB
    short* Wg       = (short*)(ws + (size_t)22 * 1024 * 1024);   // 49,152 B
    float* ctxtc    = (float*)(ws + (size_t)22 * 1024 * 1024 + 65536); // 64 KB

    // denom (1 MB) + counts (256 KB) contiguous: one memset
    hipMemsetAsync(denom, 0,
                   (size_t)NSEG * NH * sizeof(float) + (size_t)NSEG * sizeof(int),
                   stream);

    // index-only chain (independent of MLP)
    k_count<<<E_TOT / 256, 256, 0, stream>>>(batch_idx, recv_idx, counts);
    k_scan1<<<NSEG / 256, 256, 0, stream>>>(counts, tmp_excl, bsums);
    k_scan2<<<1, 256, 0, stream>>>(bsums);
    k_scan3<<<NSEG / 256, 256, 0, stream>>>(tmp_excl, bsums, offs, cursor);
    k_scatter<<<E_TOT / 256, 256, 0, stream>>>(batch_idx, recv_idx, cursor, elist);

    // MLP chain
    k_prep_w<<<96, 256, 0, stream>>>(W1, Wg);
    k_prep_ctx<<<64, 256, 0, stream>>>(W1, b1, globs, cndts, ctxtc);
    k_mlp_mfma<<<256, 512, 0, stream>>>(pooled, edges, Wg, ctxtc, W2,
                                        batch_idx, recv_idx, ex, denom);

    // final weighted pool
    k_gather<<<(NSEG * 64) / 256, 256, 0, stream>>>(new_edges, ex, denom,
                                                    offs, counts, elist, out);
}